// Round 20
// baseline (712.875 us; speedup 1.0000x reference)
//
#include <hip/hip_runtime.h>
#include <stdint.h>

#define HIST 336
#define CNTX 168
#define PRED 24
#define HID 128
#define NFEAT 5
#define EMB 50
#define NLAGS 168
#define IN_DIM 218
#define NSAMP 8192
#define G3 384

// workspace layout (float offsets)
#define WS_XS     0
#define WS_SC     336
#define WS_TF     340
#define WS_YM     8740
#define WS_KEYS   9940
#define WS_ENCGI  10036
#define WS_WQ     10036
#define WS_GISH   74548
#define WS_HLAST  83764
#define WS_WIHT   83892

typedef float v2f __attribute__((ext_vector_type(2)));
__device__ __forceinline__ v2f fma2(v2f a, v2f b, v2f c){ return __builtin_elementwise_fma(a,b,c); }

// ---------------- threefry2x32 core (20 rounds) ----------------
__device__ __forceinline__ uint32_t rotl32(uint32_t v, int r){ return (v<<r)|(v>>(32-r)); }

__device__ __forceinline__ void threefry(uint32_t k0, uint32_t k1, uint32_t x0, uint32_t x1,
                                         uint32_t &o0, uint32_t &o1){
  uint32_t ks2 = k0 ^ k1 ^ 0x1BD11BDAu;
  x0 += k0; x1 += k1;
#define TFR(a) { x0 += x1; x1 = rotl32(x1,(a)); x1 ^= x0; }
  TFR(13) TFR(15) TFR(26) TFR(6)
  x0 += k1; x1 += ks2 + 1u;
  TFR(17) TFR(29) TFR(16) TFR(24)
  x0 += ks2; x1 += k0 + 2u;
  TFR(13) TFR(15) TFR(26) TFR(6)
  x0 += k0; x1 += k1 + 3u;
  TFR(17) TFR(29) TFR(16) TFR(24)
  x0 += k1; x1 += ks2 + 4u;
  TFR(13) TFR(15) TFR(26) TFR(6)
  x0 += ks2; x1 += k0 + 5u;
#undef TFR
  o0 = x0; o1 = x1;
}

// ---------------- partitionable (foldlike) JAX PRNG semantics ----------------
__device__ __forceinline__ void tf_split2(uint32_t k0, uint32_t k1,
                                          uint32_t &a0, uint32_t &a1,
                                          uint32_t &b0, uint32_t &b1){
  threefry(k0,k1, 0u,0u, a0,a1);
  threefry(k0,k1, 0u,1u, b0,b1);
}

__device__ __forceinline__ void tf_split3(uint32_t k0, uint32_t k1,
                                          uint32_t &a0, uint32_t &a1,
                                          uint32_t &b0, uint32_t &b1,
                                          uint32_t &c0, uint32_t &c1){
  threefry(k0,k1, 0u,0u, a0,a1);
  threefry(k0,k1, 0u,1u, b0,b1);
  threefry(k0,k1, 0u,2u, c0,c1);
}

__device__ __forceinline__ uint32_t tf_bits1(uint32_t k0, uint32_t k1){
  uint32_t o0,o1; threefry(k0,k1, 0u,0u, o0,o1); return o0 ^ o1;
}

__device__ __forceinline__ uint32_t tf_bits_at(uint32_t k0, uint32_t k1, uint32_t i){
  uint32_t o0,o1; threefry(k0,k1, 0u,i, o0,o1); return o0 ^ o1;
}

__device__ __forceinline__ float bits_to_f01(uint32_t b){
  return __uint_as_float((b>>9) | 0x3f800000u) - 1.0f;
}

// XLA ErfInv32 polynomial
__device__ __forceinline__ float erfinv32(float x){
  float w = -log1pf(-x*x);
  float p;
  if (w < 5.0f){
    w = w - 2.5f;
    p = 2.81022636e-08f;
    p = fmaf(p, w, 3.43273939e-07f);
    p = fmaf(p, w, -3.5233877e-06f);
    p = fmaf(p, w, -4.39150654e-06f);
    p = fmaf(p, w, 0.00021858087f);
    p = fmaf(p, w, -0.00125372503f);
    p = fmaf(p, w, -0.00417768164f);
    p = fmaf(p, w, 0.246640727f);
    p = fmaf(p, w, 1.50140941f);
  } else {
    w = sqrtf(w) - 3.0f;
    p = -0.000200214257f;
    p = fmaf(p, w, 0.000100950558f);
    p = fmaf(p, w, 0.00134934322f);
    p = fmaf(p, w, -0.00367342844f);
    p = fmaf(p, w, 0.00573950773f);
    p = fmaf(p, w, -0.0076224613f);
    p = fmaf(p, w, 0.00943887047f);
    p = fmaf(p, w, 1.00167406f);
    p = fmaf(p, w, 2.83297682f);
  }
  return p*x;
}

__device__ __forceinline__ float normal_from_key(uint32_t k0, uint32_t k1){
  uint32_t b = tf_bits1(k0,k1);
  const float lo = -0.99999994f;
  float f = bits_to_f01(b);
  float u = fmaxf(lo, f*2.0f + lo);
  return 1.41421356f * erfinv32(u);
}

__device__ __forceinline__ float softplus_f(float x){
  float amax = fmaxf(x, 0.0f);
  return amax + log1pf(expf(-fabsf(x)));
}

// ---------------- K1: scale, xs, tf, ym, step keys ----------------
__global__ __launch_bounds__(256) void k1_prep(const float* __restrict__ x,
                                               const float* __restrict__ xmark,
                                               const float* __restrict__ ymark,
                                               const float* __restrict__ Wemb,
                                               const float* __restrict__ bemb,
                                               float* __restrict__ ws){
  __shared__ float red[256];
  __shared__ float s_sc;
  int t = threadIdx.x;
  float a = 0.f;
  if (t < CNTX) a = fabsf(x[CNTX + t]);
  red[t] = a;
  __syncthreads();
  for(int s=128; s>0; s>>=1){ if(t<s) red[t]+=red[t+s]; __syncthreads(); }
  if (t==0){ s_sc = fmaxf(red[0]/168.0f, 1e-5f); ws[WS_SC]=s_sc; }
  __syncthreads();
  float sc = s_sc;
  for(int i=t; i<HIST; i+=256) ws[WS_XS+i] = x[i]/sc;
  for(int idx=t; idx<CNTX*EMB; idx+=256){
    int tt = idx/EMB, e = idx%EMB;
    float acc = bemb[e];
    for(int f=0; f<NFEAT; f++) acc += xmark[(CNTX+tt)*NFEAT+f]*Wemb[f*EMB+e];
    ws[WS_TF+idx] = acc;
  }
  for(int idx=t; idx<PRED*EMB; idx+=256){
    int kk = idx/EMB, e = idx%EMB;
    float acc = bemb[e];
    for(int f=0; f<NFEAT; f++) acc += ymark[kk*NFEAT+f]*Wemb[f*EMB+e];
    ws[WS_YM+idx] = acc;
  }
  if (t==0){
    uint32_t* kp = reinterpret_cast<uint32_t*>(ws + WS_KEYS);
    uint32_t c0 = 0u, c1 = 42u;
    for(int k=0;k<PRED;k++){
      uint32_t a0,a1,b0,b1;
      tf_split2(c0,c1, a0,a1, b0,b1);
      c0=a0; c1=a1;
      uint32_t n0,n1,g0,g1;
      tf_split2(b0,b1, n0,n1, g0,g1);
      kp[k*4+0]=n0; kp[k*4+1]=n1; kp[k*4+2]=g0; kp[k*4+3]=g1;
    }
  }
}

// ---------------- K2: enc_gi / gi_shared (broadcast W rows) + fused wihT transpose ----
__global__ __launch_bounds__(256) void k2_gi(const float* __restrict__ Wih,
                                             const float* __restrict__ bih,
                                             const float* __restrict__ bhh,
                                             float* __restrict__ ws){
  int idx = blockIdx.x*256 + threadIdx.x;
  if (idx < G3*192){
    int r = idx / 192, t = idx % 192;
    const float* wr = Wih + r*IN_DIM;
    const float* xs = ws + WS_XS;
    float acc = bih[r] + (r < 256 ? bhh[r] : 0.0f);
    if (t < CNTX){
      const float* tf = ws + WS_TF + t*EMB;
      for(int j=0;j<NLAGS;j++) acc += wr[j]*xs[CNTX + t - 1 - j];
      for(int e=0;e<EMB;e++)   acc += wr[NLAGS+e]*tf[e];
      ws[WS_ENCGI + t*G3 + r] = acc;
    } else {
      int k = t - CNTX;
      const float* ym = ws + WS_YM + k*EMB;
      for(int e=0;e<EMB;e++)   acc += wr[NLAGS+e]*ym[e];
      for(int i=k;i<NLAGS;i++) acc += wr[i]*xs[HIST-1-i+k];
      ws[WS_GISH + k*G3 + r] = acc;
    }
  } else {
    int j = idx - G3*192;
    if (j < PRED*G3){
      int r = j / PRED, i = j % PRED;
      ws[WS_WIHT + i*G3 + r] = Wih[r*IN_DIM + i];
    }
  }
}

// ---------------- K3: encoder GRU + fused Wq build ----------
__global__ __launch_bounds__(384) void k3_enc(const float* __restrict__ Whh,
                                              const float* __restrict__ bhh,
                                              float* __restrict__ ws){
  __shared__ __align__(16) float h[HID];
  __shared__ float grz[256];
  __shared__ float hnv[HID];
  int r = threadIdx.x;
  float4 w[32];
  const float4* wr = (const float4*)(Whh + r*HID);
  #pragma unroll
  for(int i=0;i<32;i++) w[i] = wr[i];
  float bh = (r>=256)? bhh[r] : 0.0f;
  if (r < HID) h[r] = 0.0f;
  __syncthreads();
  const float* encgi = ws + WS_ENCGI;
  for(int t=0;t<CNTX;t++){
    float acc = 0.f;
    #pragma unroll
    for(int i=0;i<32;i++){
      float4 hv = *(const float4*)&h[4*i];
      float4 ww = w[i];
      acc = fmaf(ww.x,hv.x, fmaf(ww.y,hv.y, fmaf(ww.z,hv.z, fmaf(ww.w,hv.w, acc))));
    }
    if (r < 256) grz[r] = encgi[t*G3+r] + acc;
    else         hnv[r-256] = acc + bh;
    __syncthreads();
    if (r < HID){
      float rr = 1.0f/(1.0f+expf(-grz[r]));
      float zz = 1.0f/(1.0f+expf(-grz[128+r]));
      float inv = encgi[t*G3+256+r];
      float nn = tanhf(inv + rr*hnv[r]);
      h[r] = (1.0f-zz)*nn + zz*h[r];
    }
    __syncthreads();
  }
  if (r < HID) ws[WS_HLAST + r] = h[r];
  // fused Wq build into the now-dead ENCGI region
  float4* wq = (float4*)(ws + WS_WQ);
  for(int idx=r; idx<32*G3; idx+=384){
    int q = idx / G3, rr = idx % G3;
    wq[idx] = *(const float4*)&Whh[rr*HID + q*4];
  }
}

// ---------------- K4: decoder — r10 matvec/gates + hoisted RNG + in-wave proj/sampling ----
#define SPB 32
#define THR4 512

__global__ __launch_bounds__(512) void k4_dec(const float* __restrict__ Whh,
                                              const float* __restrict__ bhh,
                                              const float* __restrict__ Wproj,
                                              const float* __restrict__ bproj,
                                              const float* __restrict__ ws,
                                              float* __restrict__ out){
  __shared__ __align__(16) float4 hT4[128][9];   // 18.4 KB
  __shared__ float wihT_l[24*G3];                // 36.9 KB
  __shared__ float shistT[25][34];               // 3.4 KB
  __shared__ float wp[HID*3];
  __shared__ float bp[3];
  __shared__ uint32_t skeys[PRED*4];
  // hoisted df-independent RNG state (bit-identical to original consumption)
  __shared__ float nv[PRED][SPB];                // normal draw for t()
  __shared__ float gx1[PRED][SPB];               // gamma iter-1 first x
  __shared__ float gU1[PRED][SPB];               // gamma iter-1 U
  __shared__ uint32_t gnk[PRED][SPB][2];         // continuation outer key (nk)
  __shared__ uint32_t gxa[PRED][SPB][2];         // continuation inner x-key (xa)

  int t = threadIdx.x;
  int b = blockIdx.x;
  int rg = t & 127;
  int sg = t >> 7;
  int s0 = sg*8;
  int g0 = sg*2;

  float bhn = bhh[256 + rg];

  for(int idx=t; idx<24*G3; idx+=THR4) wihT_l[idx] = ws[WS_WIHT + idx];
  for(int idx=t; idx<HID*3; idx+=THR4) wp[idx] = Wproj[idx];
  if (t < 3) bp[t] = bproj[t];
  if (t < PRED*4) skeys[t] = reinterpret_cast<const uint32_t*>(ws + WS_KEYS)[t];
  if (t < 128){
    float hl = ws[WS_HLAST + t];
    float4 v = {hl,hl,hl,hl};
    #pragma unroll
    for(int g=0;g<8;g++) hT4[t][g] = v;
  }
  float hold[8];
  {
    float hl = ws[WS_HLAST + rg];
    #pragma unroll
    for(int s=0;s<8;s++) hold[s] = hl;
  }
  float sc = ws[WS_SC];
  const float* gish = ws + WS_GISH;
  const float4* Wq4 = (const float4*)(ws + WS_WQ);
  __syncthreads();

  // ---- one-time hoist: df-independent RNG draws for all (k, s) ----
  for(int idx=t; idx<PRED*SPB; idx+=THR4){
    int kk = idx >> 5, s = idx & 31;
    uint32_t gs = (uint32_t)(b*SPB + s);
    uint32_t kn0 = skeys[kk*4+0], kn1 = skeys[kk*4+1];
    uint32_t kg0 = skeys[kk*4+2], kg1 = skeys[kk*4+3];
    // normal draw for the t-distribution (key_n)
    uint32_t bnb = tf_bits_at(kn0, kn1, gs);
    const float lo = -0.99999994f;
    float un = fmaxf(lo, bits_to_f01(bnb)*2.0f + lo);
    nv[kk][s] = 1.41421356f * erfinv32(un);
    // gamma key chain prefix (key_g — identical consumption to r5..r18 gamma_sample)
    uint32_t gk0,gk1; threefry(kg0, kg1, 0u, gs, gk0, gk1);
    uint32_t ck0,ck1, sb0,sb1;
    tf_split2(gk0,gk1, ck0,ck1, sb0,sb1);       // (key, boost-subkey: unused, alpha>=1)
    uint32_t nk0,nk1, xk0,xk1, uk0,uk1;
    tf_split3(ck0,ck1, nk0,nk1, xk0,xk1, uk0,uk1);
    uint32_t xa0,xa1, xb0,xb1;
    tf_split2(xk0,xk1, xa0,xa1, xb0,xb1);
    gx1[kk][s] = normal_from_key(xb0,xb1);
    gU1[kk][s] = bits_to_f01(tf_bits1(uk0,uk1));
    gnk[kk][s][0]=nk0; gnk[kk][s][1]=nk1;
    gxa[kk][s][0]=xa0; gxa[kk][s][1]=xa1;
  }
  __syncthreads();

  #pragma unroll 1
  for(int k=0;k<PRED;k++){
    v2f aR[4], aZ[4], aH[4], aI[4];
    {
      float gR = gish[k*G3 + rg];
      float gZ = gish[k*G3 + 128 + rg];
      float gI = gish[k*G3 + 256 + rg];
      #pragma unroll
      for(int p=0;p<4;p++){
        aR[p] = (v2f){gR,gR}; aZ[p] = (v2f){gZ,gZ};
        aI[p] = (v2f){gI,gI}; aH[p] = (v2f){bhn,bhn};
      }
    }
    // lag chains (i ascending — identical order)
    #pragma unroll 1
    for(int i=0;i<k;i++){
      float wR = wihT_l[i*G3 + rg];
      float wZ = wihT_l[i*G3 + 128 + rg];
      float wN = wihT_l[i*G3 + 256 + rg];
      v2f wR2 = {wR,wR}, wZ2 = {wZ,wZ}, wN2 = {wN,wN};
      #pragma unroll
      for(int p=0;p<4;p++){
        v2f sh = *(const v2f*)&shistT[k-1-i][s0 + 2*p];
        aR[p] = fma2(wR2, sh, aR[p]);
        aZ[p] = fma2(wZ2, sh, aZ[p]);
        aI[p] = fma2(wN2, sh, aI[p]);
      }
    }
    // main W.h: q ascending, c=0..3 -> dims ascending (identical chain)
    #pragma unroll 1
    for(int q=0;q<32;q++){
      float4 wr4 = Wq4[q*G3 + rg];
      float4 wz4 = Wq4[q*G3 + 128 + rg];
      float4 wn4 = Wq4[q*G3 + 256 + rg];
      #pragma unroll
      for(int c=0;c<4;c++){
        float wrc = (c==0)?wr4.x:(c==1)?wr4.y:(c==2)?wr4.z:wr4.w;
        float wzc = (c==0)?wz4.x:(c==1)?wz4.y:(c==2)?wz4.z:wz4.w;
        float wnc = (c==0)?wn4.x:(c==1)?wn4.y:(c==2)?wn4.z:wn4.w;
        v2f wr2 = {wrc,wrc}, wz2 = {wzc,wzc}, wn2 = {wnc,wnc};
        #pragma unroll
        for(int g=0;g<2;g++){
          float4 hv = hT4[4*q + c][g0 + g];
          v2f lo = {hv.x, hv.y}, hi = {hv.z, hv.w};
          aR[2*g]   = fma2(wr2, lo, aR[2*g]);
          aR[2*g+1] = fma2(wr2, hi, aR[2*g+1]);
          aZ[2*g]   = fma2(wz2, lo, aZ[2*g]);
          aZ[2*g+1] = fma2(wz2, hi, aZ[2*g+1]);
          aH[2*g]   = fma2(wn2, lo, aH[2*g]);
          aH[2*g+1] = fma2(wn2, hi, aH[2*g+1]);
        }
      }
    }
    __syncthreads();   // all hT4 (old h) reads complete
    // gates fused in-thread (identical per-cell formulas)
    #pragma unroll
    for(int s=0;s<8;s++){
      int p = s >> 1, e = s & 1;
      float aRv = aR[p][e], aZv = aZ[p][e], aIv = aI[p][e], aHv = aH[p][e];
      float rr = 1.0f/(1.0f+expf(-aRv));
      float zz = 1.0f/(1.0f+expf(-aZv));
      float nn = tanhf(aIv + rr*aHv);
      float hn = (1.0f-zz)*nn + zz*hold[s];
      hold[s] = hn;
      ((float*)&hT4[rg][g0 + (s>>2)])[s & 3] = hn;
    }
    __syncthreads();
    // projection + sampling merged on 32 threads (per-output chains identical)
    if (t < SPB){
      int s = t, gs = b*SPB + s;
      const float* hT = (const float*)hT4;
      float p0 = bp[0], p1 = bp[1], p2 = bp[2];
      for(int l=0;l<HID;l++){
        float hv = hT[l*36 + s];
        p0 = fmaf(hv, wp[l*3+0], p0);
        p1 = fmaf(hv, wp[l*3+1], p1);
        p2 = fmaf(hv, wp[l*3+2], p2);
      }
      float loc = p1;
      float df = 2.0f + softplus_f(p0);
      float half_df = df*0.5f;
      float sigma = softplus_f(p2);
      // gamma resume (identical key consumption; iteration-1 draws precomputed)
      float d_ = __fsub_rn(half_df, 0.33333334f);
      float c_ = 0.33333334f / sqrtf(d_);
      float x = gx1[k][s];
      float U = gU1[k][s];
      uint32_t xk0 = gxa[k][s][0], xk1 = gxa[k][s][1];
      uint32_t ck0 = gnk[k][s][0], ck1 = gnk[k][s][1];
      float v = __fadd_rn(1.0f, __fmul_rn(x, c_));
      while (v <= 0.0f){
        uint32_t xa0,xa1, xb0,xb1;
        tf_split2(xk0,xk1, xa0,xa1, xb0,xb1);
        xk0=xa0; xk1=xa1;
        x = normal_from_key(xb0,xb1);
        v = __fadd_rn(1.0f, __fmul_rn(x, c_));
      }
      float V; bool done = false;
      {
        float X  = __fmul_rn(x, x);
        float Vv = __fmul_rn(__fmul_rn(v, v), v);
        float t1 = __fsub_rn(1.0f, __fmul_rn(0.0331f, __fmul_rn(X, X)));
        bool cont = (U >= t1);
        if (cont){
          float lhs = logf(U);
          float rhs = __fadd_rn(__fmul_rn(0.5f, X),
                      __fmul_rn(d_, __fadd_rn(__fsub_rn(1.0f, Vv), logf(Vv))));
          cont = (lhs >= rhs);
        }
        if (!cont){ V = Vv; done = true; }
      }
      if (!done){
        for(;;){
          uint32_t nk0,nk1, xkb0,xkb1, uk0,uk1;
          tf_split3(ck0,ck1, nk0,nk1, xkb0,xkb1, uk0,uk1);
          ck0=nk0; ck1=nk1;
          float xx, vv;
          uint32_t xc0 = xkb0, xc1 = xkb1;
          do {
            uint32_t xa0,xa1, xb0,xb1;
            tf_split2(xc0,xc1, xa0,xa1, xb0,xb1);
            xc0=xa0; xc1=xa1;
            xx = normal_from_key(xb0,xb1);
            vv = __fadd_rn(1.0f, __fmul_rn(xx, c_));
          } while (vv <= 0.0f);
          float X  = __fmul_rn(xx, xx);
          float Vv = __fmul_rn(__fmul_rn(vv, vv), vv);
          float Uu = bits_to_f01(tf_bits1(uk0,uk1));
          float t1 = __fsub_rn(1.0f, __fmul_rn(0.0331f, __fmul_rn(X, X)));
          bool cont = (Uu >= t1);
          if (cont){
            float lhs = logf(Uu);
            float rhs = __fadd_rn(__fmul_rn(0.5f, X),
                        __fmul_rn(d_, __fadd_rn(__fsub_rn(1.0f, Vv), logf(Vv))));
            cont = (lhs >= rhs);
          }
          if (!cont){ V = Vv; break; }
        }
      }
      float gmm = d_*V;
      float nval = nv[k][s];
      float tval = nval * sqrtf(half_df / gmm);
      float samp = (loc + sigma*tval)*sc;
      out[gs*PRED + k] = samp;
      shistT[k][s] = samp / sc;
    }
    __syncthreads();
  }
}

extern "C" void kernel_launch(void* const* d_in, const int* in_sizes, int n_in,
                              void* d_out, int out_size, void* d_ws, size_t ws_size,
                              hipStream_t stream){
  const float* x     = (const float*)d_in[0];
  const float* xmark = (const float*)d_in[1];
  const float* ymark = (const float*)d_in[2];
  const float* Wemb  = (const float*)d_in[3];
  const float* bemb  = (const float*)d_in[4];
  const float* Wih   = (const float*)d_in[5];
  const float* Whh   = (const float*)d_in[6];
  const float* bih   = (const float*)d_in[7];
  const float* bhh   = (const float*)d_in[8];
  const float* Wproj = (const float*)d_in[9];
  const float* bproj = (const float*)d_in[10];
  float* ws  = (float*)d_ws;
  float* out = (float*)d_out;

  hipLaunchKernelGGL(k1_prep, dim3(1), dim3(256), 0, stream, x, xmark, ymark, Wemb, bemb, ws);
  hipLaunchKernelGGL(k2_gi, dim3((G3*192 + PRED*G3 + 255)/256), dim3(256), 0, stream, Wih, bih, bhh, ws);
  hipLaunchKernelGGL(k3_enc, dim3(1), dim3(384), 0, stream, Whh, bhh, ws);
  hipLaunchKernelGGL(k4_dec, dim3(NSAMP/SPB), dim3(THR4), 0, stream, Whh, bhh, Wproj, bproj, ws, out);
}